// Round 1
// baseline (1052.804 us; speedup 1.0000x reference)
//
#include <hip/hip_runtime.h>
#include <math.h>

#define NB 2
#define CIN 64
#define DD_ 64
#define HH_ 64
#define WW_ 64
#define NCLS 5
#define LL (DD_*HH_*WW_)   /* 262144 */
#define NMAXG 32
#define TOPKK 13
#define SEG 4
#define SEGL (LL/SEG)      /* 65536 */

__device__ __forceinline__ float softplusf_(float z){
  return fmaxf(z, 0.f) + log1pf(expf(-fabsf(z)));
}
__device__ __forceinline__ float sigmoidf_(float z){
  return 1.f/(1.f + expf(-z));
}

// ---------------- Phase A: conv (8 ch) + store logits/centers + background cls-loss sum
__global__ __launch_bounds__(256) void conv_loss_kernel(
    const float* __restrict__ feat,
    const float* __restrict__ cls_w, const float* __restrict__ cls_b,
    const float* __restrict__ off_w, const float* __restrict__ off_b,
    float* __restrict__ logits_ws,   // [B][5][L]
    float* __restrict__ centers_ws,  // [B][3][L]
    float* __restrict__ bg_sum)      // [1]
{
  const int w  = threadIdx.x;               // 0..63
  const int h  = blockIdx.x*4 + threadIdx.y;
  const int d0 = blockIdx.y*2;
  const int b  = blockIdx.z;

  float acc[8][2];
  #pragma unroll
  for (int o=0;o<8;++o){ acc[o][0]=0.f; acc[o][1]=0.f; }

  float dmask[4]; int ddc[4];
  #pragma unroll
  for (int i=0;i<4;++i){
    int dd = d0-1+i;
    dmask[i] = (dd>=0 && dd<DD_) ? 1.f : 0.f;
    ddc[i]   = dd<0?0:(dd>63?63:dd);
  }

  const float* fb = feat + (size_t)b*CIN*LL;
  #pragma unroll 1
  for (int c=0;c<CIN;++c){
    const float* fc = fb + c*LL;
    #pragma unroll
    for (int kh=0;kh<3;++kh){
      int hh = h + kh - 1;
      float hm = (hh>=0 && hh<HH_) ? 1.f : 0.f;
      int hhc = hh<0?0:(hh>63?63:hh);
      #pragma unroll
      for (int kw=0;kw<3;++kw){
        int wp = w + kw - 1;
        float wm = (wp>=0 && wp<WW_) ? 1.f : 0.f;
        int wwc = wp<0?0:(wp>63?63:wp);
        const float hwm = hm*wm;
        const float* p = fc + hhc*WW_ + wwc;
        float x[4];
        #pragma unroll
        for (int i=0;i<4;++i)
          x[i] = p[ddc[i]*(HH_*WW_)] * (hwm*dmask[i]);
        #pragma unroll
        for (int kd=0;kd<3;++kd){
          float wv[8];
          #pragma unroll
          for (int o=0;o<NCLS;++o)
            wv[o] = cls_w[(((o*CIN + c)*3 + kd)*3 + kh)*3 + kw];   // uniform -> s_load
          #pragma unroll
          for (int o=0;o<3;++o)
            wv[NCLS+o] = off_w[(((o*CIN + c)*3 + kd)*3 + kh)*3 + kw];
          #pragma unroll
          for (int di=0;di<2;++di){
            float xv = x[di+kd];
            #pragma unroll
            for (int o=0;o<8;++o)
              acc[o][di] = fmaf(xv, wv[o], acc[o][di]);
          }
        }
      }
    }
  }

  float part = 0.f;
  #pragma unroll
  for (int di=0;di<2;++di){
    int l = (d0+di)*(HH_*WW_) + h*WW_ + w;
    #pragma unroll
    for (int o=0;o<NCLS;++o){
      float z = acc[o][di] + cls_b[o];
      logits_ws[(b*NCLS+o)*LL + l] = z;
      float pr = sigmoidf_(z);
      part += 0.75f*pr*pr*softplusf_(z);  // background cls term (corrected later at fg)
    }
    float c0 = ((float)(d0+di)+0.5f)*2.f + acc[5][di] + off_b[0];
    float c1 = ((float)h+0.5f)*2.f       + acc[6][di] + off_b[1];
    float c2 = ((float)w+0.5f)*2.f       + acc[7][di] + off_b[2];
    centers_ws[(b*3+0)*LL + l] = c0;
    centers_ws[(b*3+1)*LL + l] = c1;
    centers_ws[(b*3+2)*LL + l] = c2;
  }

  #pragma unroll
  for (int off=32;off;off>>=1) part += __shfl_down(part, off);
  __shared__ float wsum[4];
  int tid = threadIdx.y*64 + threadIdx.x;
  if ((tid & 63)==0) wsum[tid>>6] = part;
  __syncthreads();
  if (tid==0) atomicAdd(bg_sum, wsum[0]+wsum[1]+wsum[2]+wsum[3]);
}

// ---------------- Phase B: per-(b,n,segment) top-13 of align over L/4 anchors
__global__ __launch_bounds__(256) void topk_partial_kernel(
    const float* __restrict__ logits_ws, const float* __restrict__ centers_ws,
    const float* __restrict__ labels,    // [B][32][5]
    float* __restrict__ pv, int* __restrict__ pi)  // [64][SEG][13]
{
  const int bn = blockIdx.x;           // 0..63
  const int seg = blockIdx.y;          // 0..SEG-1
  const int b = bn >> 5, n = bn & 31;
  const int tid = threadIdx.x;

  const float* lb = labels + (b*NMAXG + n)*5;
  const float tx = lb[0], ty = lb[1], tz = lb[2];
  const float cf = lb[3];
  const float sg = lb[4];
  const int lab = (cf == -100.f) ? 0 : (int)cf;   // where(valid, cls, 0)
  const float m6 = -3.f/(sg*sg);                  // iou^6 = exp(-3*d2/sigma^2)

  const float* lg = logits_ws + (size_t)(b*NCLS + lab)*LL;
  const float* cx = centers_ws + (size_t)(b*3+0)*LL;
  const float* cy = centers_ws + (size_t)(b*3+1)*LL;
  const float* cz = centers_ws + (size_t)(b*3+2)*LL;

  float v[13]; int ix[13];
  #pragma unroll
  for (int j=0;j<13;++j){ v[j]=-1.f; ix[j]=0x7fffffff; }

  const int l0 = seg*SEGL;
  for (int l = l0 + tid; l < l0 + SEGL; l += 256){
    float dx = cx[l]-tx, dy = cy[l]-ty, dz = cz[l]-tz;
    float d2 = dx*dx + dy*dy + dz*dz;
    float a = sigmoidf_(lg[l]) * expf(m6*d2);
    if (a > v[12]){
      float cv = a; int ci = l;
      #pragma unroll
      for (int j=0;j<13;++j){   // compare-swap cascade, all static indices
        bool take = (cv > v[j]) || (cv == v[j] && ci < ix[j]);
        float nv = take ? cv : v[j];  float ov = take ? v[j] : cv;
        int   ni = take ? ci : ix[j]; int   oi = take ? ix[j] : ci;
        v[j]=nv; ix[j]=ni; cv=ov; ci=oi;
      }
    }
  }

  __shared__ float sv[256*13];
  __shared__ int   si[256*13];
  #pragma unroll
  for (int j=0;j<13;++j){ sv[tid*13+j]=v[j]; si[tid*13+j]=ix[j]; }
  __syncthreads();
  __shared__ float rv[256]; __shared__ int ri[256]; __shared__ int rs[256];
  for (int k=0;k<13;++k){
    float bv=-2.f; int bi=0x7fffffff; int bs=-1;
    #pragma unroll
    for (int j=0;j<13;++j){
      float x = sv[tid*13+j]; int xi = si[tid*13+j];
      if (x>bv || (x==bv && xi<bi)){ bv=x; bi=xi; bs=tid*13+j; }
    }
    rv[tid]=bv; ri[tid]=bi; rs[tid]=bs;
    __syncthreads();
    for (int s2=128;s2;s2>>=1){
      if (tid<s2){
        if (rv[tid+s2]>rv[tid] || (rv[tid+s2]==rv[tid] && ri[tid+s2]<ri[tid])){
          rv[tid]=rv[tid+s2]; ri[tid]=ri[tid+s2]; rs[tid]=rs[tid+s2];
        }
      }
      __syncthreads();
    }
    if (tid==0){
      pv[(bn*SEG+seg)*TOPKK + k] = rv[0];
      pi[(bn*SEG+seg)*TOPKK + k] = ri[0];
      if (rs[0]>=0) sv[rs[0]] = -2.f;
    }
    __syncthreads();
  }
}

// ---------------- Phase B2: merge SEG partial top-13s -> global top-13 per (b,n)
__global__ __launch_bounds__(64) void topk_merge_kernel(
    const float* __restrict__ pv, const int* __restrict__ pi,
    float* __restrict__ tv, int* __restrict__ ti)
{
  const int bn = blockIdx.x;
  const int t = threadIdx.x;       // 64
  const int NC = SEG*TOPKK;        // 52
  float v = -2.f; int ix = 0x7fffffff;
  if (t < NC){ v = pv[bn*NC + t]; ix = pi[bn*NC + t]; }
  for (int k=0;k<13;++k){
    float bv = v; int bi = ix; int bl = t;
    #pragma unroll
    for (int off=32; off; off>>=1){
      float ov = __shfl_xor(bv, off);
      int oi = __shfl_xor(bi, off);
      int ol = __shfl_xor(bl, off);
      if (ov > bv || (ov == bv && oi < bi)){ bv=ov; bi=oi; bl=ol; }
    }
    if (t==0){ tv[bn*TOPKK+k]=bv; ti[bn*TOPKK+k]=bi; }
    if (t==bl) v = -2.f;
  }
}

// ---------------- Phase C: candidate resolution + corrections + reg loss + final scalar
__global__ __launch_bounds__(256) void finalize_kernel(
    const float* __restrict__ logits_ws, const float* __restrict__ centers_ws,
    const float* __restrict__ labels,
    const float* __restrict__ tv, const int* __restrict__ ti,
    const float* __restrict__ bg_sum, float* __restrict__ out)
{
  const int tid = threadIdx.x;   // 256
  __shared__ float gx[32], gy[32], gz[32], gs[32];
  __shared__ int glab[32], gvalid[32];
  __shared__ int   ent_l[416];
  __shared__ int   ent_ok[416];
  __shared__ int   ent_first[416];
  __shared__ int   ent_n[416];
  __shared__ float ent_a[416], ent_i[416];
  __shared__ unsigned maxA[32], maxI[32];
  __shared__ float accD, accC;   // denom, corr+reg
  if (tid==0){ accD=0.f; accC=0.f; }

  for (int b=0;b<NB;++b){
    if (tid<32){
      const float* lb = labels + (b*NMAXG + tid)*5;
      gx[tid]=lb[0]; gy[tid]=lb[1]; gz[tid]=lb[2];
      float cf = lb[3]; gs[tid]=lb[4];
      int val = (cf != -100.f);
      gvalid[tid]=val; glab[tid]= val ? (int)cf : 0;
      maxA[tid]=0u; maxI[tid]=0u;
    }
    __syncthreads();
    for (int e=tid;e<416;e+=256){
      int n = e/13, k = e - 13*n;
      float v = tv[(b*NMAXG+n)*TOPKK + k];
      ent_l[e]  = ti[(b*NMAXG+n)*TOPKK + k];
      ent_ok[e] = gvalid[n] && (v > 1e-9f);
      ent_first[e]=0; ent_n[e]=-1; ent_a[e]=0.f; ent_i[e]=0.f;
    }
    __syncthreads();
    for (int e=tid;e<416;e+=256){
      if (!ent_ok[e]) continue;
      int l = ent_l[e]; int cnt=0; int first=1;
      for (int e2=0;e2<416;++e2){
        if (ent_ok[e2] && ent_l[e2]==l){ cnt++; if (e2<e) first=0; }
      }
      if (!first) continue;
      ent_first[e]=1;
      float px = centers_ws[(size_t)(b*3+0)*LL + l];
      float py = centers_ws[(size_t)(b*3+1)*LL + l];
      float pz = centers_ws[(size_t)(b*3+2)*LL + l];
      int nstar;
      if (cnt==1){
        nstar = e/13;
      } else {
        // pos_sum>1 -> assign by argmax_n ious (ALL n, incl invalid; first-tie)
        float best = -1.f; int bidx = 0;
        for (int nn=0;nn<32;++nn){
          float dx=gx[nn]-px, dy=gy[nn]-py, dz=gz[nn]-pz;
          float d2 = dx*dx+dy*dy+dz*dz;
          float iou = expf(-d2/(2.f*gs[nn]*gs[nn]));
          if (iou > best){ best=iou; bidx=nn; }
        }
        nstar = bidx;
      }
      ent_n[e] = nstar;
      float dx=gx[nstar]-px, dy=gy[nstar]-py, dz=gz[nstar]-pz;
      float d2 = dx*dx+dy*dy+dz*dz;
      float sgv = gs[nstar];
      float iou = expf(-d2/(2.f*sgv*sgv));
      float z = logits_ws[(size_t)(b*NCLS + glab[nstar])*LL + l];
      float a = sigmoidf_(z) * expf(-3.f*d2/(sgv*sgv));
      ent_a[e]=a; ent_i[e]=iou;
      atomicMax(&maxA[nstar], __float_as_uint(a));
      atomicMax(&maxI[nstar], __float_as_uint(iou));
    }
    __syncthreads();
    for (int e=tid;e<416;e+=256){
      if (!ent_first[e]) continue;
      int l = ent_l[e]; int nstar = ent_n[e];
      float mA = __uint_as_float(maxA[nstar]);
      float mI = __uint_as_float(maxI[nstar]);
      float score = ent_a[e]*mI/(mA + 1e-9f);
      int lab = glab[nstar];
      float z = logits_ws[(size_t)(b*NCLS + lab)*LL + l];
      float p = sigmoidf_(z);
      float t2 = log1pf(expf(-fabsf(z)));
      float spz = fmaxf(z,0.f) + t2;
      float spm = fmaxf(-z,0.f) + t2;
      // replace base background term at (l, lab) with true fg term
      float corr = score*(score*spm + (1.f-score)*spz) - 0.75f*p*p*spz;
      float reg  = (1.f - ent_i[e])*score;
      atomicAdd(&accD, score);
      atomicAdd(&accC, corr + reg);
    }
    __syncthreads();
  }
  if (tid==0) out[0] = (bg_sum[0] + accC) / accD;
}

extern "C" void kernel_launch(void* const* d_in, const int* in_sizes, int n_in,
                              void* d_out, int out_size, void* d_ws, size_t ws_size,
                              hipStream_t stream) {
  const float* feat  = (const float*)d_in[0];
  const float* cls_w = (const float*)d_in[1];
  const float* cls_b = (const float*)d_in[2];
  const float* off_w = (const float*)d_in[3];
  const float* off_b = (const float*)d_in[4];
  const float* labels= (const float*)d_in[5];
  float* out = (float*)d_out;

  float* logits_ws  = (float*)d_ws;                              // 2*5*L
  float* centers_ws = logits_ws + (size_t)NB*NCLS*LL;            // 2*3*L
  float* pv = centers_ws + (size_t)NB*3*LL;                      // 64*SEG*13
  int*   pi = (int*)(pv + 64*SEG*TOPKK);
  float* tv = (float*)(pi + 64*SEG*TOPKK);                       // 64*13
  int*   ti = (int*)(tv + 64*TOPKK);
  float* bg = (float*)(ti + 64*TOPKK);                           // 1

  hipMemsetAsync(bg, 0, sizeof(float), stream);

  conv_loss_kernel<<<dim3(16,32,2), dim3(64,4,1), 0, stream>>>(
      feat, cls_w, cls_b, off_w, off_b, logits_ws, centers_ws, bg);
  topk_partial_kernel<<<dim3(64,SEG), 256, 0, stream>>>(
      logits_ws, centers_ws, labels, pv, pi);
  topk_merge_kernel<<<64, 64, 0, stream>>>(pv, pi, tv, ti);
  finalize_kernel<<<1, 256, 0, stream>>>(
      logits_ws, centers_ws, labels, tv, ti, bg, out);
}

// Round 2
// 508.490 us; speedup vs baseline: 2.0705x; 2.0705x over previous
//
#include <hip/hip_runtime.h>
#include <math.h>

#define NB 2
#define CIN 64
#define DD_ 64
#define HH_ 64
#define WW_ 64
#define NCLS 5
#define LL (DD_*HH_*WW_)   /* 262144 */
#define NMAXG 32
#define TOPKK 13
#define SEG 16
#define SEGL (LL/SEG)      /* 16384 */

__device__ __forceinline__ float softplusf_(float z){
  return fmaxf(z, 0.f) + log1pf(expf(-fabsf(z)));
}
__device__ __forceinline__ float sigmoidf_(float z){
  return 1.f/(1.f + expf(-z));
}

// ---------------- Phase 0: transpose weights to [c][kd][kh][kw][8]
__global__ __launch_bounds__(256) void wtrans_kernel(
    const float* __restrict__ cls_w, const float* __restrict__ off_w,
    float* __restrict__ wT)
{
  for (int idx = threadIdx.x; idx < CIN*27*8; idx += 256){
    int o = idx & 7;
    int r = idx >> 3;          // c*27 + (kd*3+kh)*3+kw
    int c = r / 27;
    int k = r - c*27;          // (kd*3+kh)*3+kw
    float v;
    if (o < NCLS) v = cls_w[(o*CIN + c)*27 + k];
    else          v = off_w[((o-NCLS)*CIN + c)*27 + k];
    wT[idx] = v;
  }
}

// ---------------- Phase A: conv (8 ch), 4 w-outputs per thread
__global__ __launch_bounds__(256) void conv_loss_kernel(
    const float* __restrict__ feat,
    const float* __restrict__ wT,
    const float* __restrict__ cls_b, const float* __restrict__ off_b,
    float* __restrict__ logits_ws,   // [B][5][L]
    float* __restrict__ centers_ws,  // [B][L][4]
    float* __restrict__ bg_sum)      // [1]
{
  const int tx = threadIdx.x;          // 0..15 (w tile)
  const int ty = threadIdx.y;          // 0..15 (h)
  const int w0 = tx*4;
  const int h  = blockIdx.x*16 + ty;
  const int d  = blockIdx.y;
  const int b  = blockIdx.z;

  float acc[8][4];
  #pragma unroll
  for (int o=0;o<8;++o)
    #pragma unroll
    for (int wl=0;wl<4;++wl) acc[o][wl]=0.f;

  float dmask[3]; int doff[3];
  #pragma unroll
  for (int kd=0;kd<3;++kd){
    int dd = d-1+kd;
    dmask[kd] = (dd>=0 && dd<DD_) ? 1.f : 0.f;
    int ddc = dd<0?0:(dd>63?63:dd);
    doff[kd] = ddc*(HH_*WW_);
  }
  const float lm = (tx>0) ?1.f:0.f; const int lo = (tx>0) ?-1:0;
  const float rm = (tx<15)?1.f:0.f; const int ro = (tx<15)? 4:3;

  const float* fb = feat + (size_t)b*CIN*LL;
  #pragma unroll 1
  for (int c=0;c<CIN;++c){
    const float* fc = fb + (size_t)c*LL;
    const float* wc = wT + c*27*8;
    #pragma unroll
    for (int kh=0;kh<3;++kh){
      int hh = h + kh - 1;
      float hm = (hh>=0 && hh<HH_) ? 1.f : 0.f;
      int hr = (hh<0?0:(hh>63?63:hh))*WW_;
      float xv[3][6];
      #pragma unroll
      for (int kd=0;kd<3;++kd){
        const float* bp = fc + doff[kd] + hr + w0;
        float m = hm*dmask[kd];
        float4 x4 = *(const float4*)bp;
        xv[kd][0]=bp[lo]*(m*lm);
        xv[kd][1]=x4.x*m; xv[kd][2]=x4.y*m;
        xv[kd][3]=x4.z*m; xv[kd][4]=x4.w*m;
        xv[kd][5]=bp[ro]*(m*rm);
      }
      #pragma unroll
      for (int kd=0;kd<3;++kd){
        #pragma unroll
        for (int kw=0;kw<3;++kw){
          const float* wp = wc + ((kd*3+kh)*3+kw)*8;
          #pragma unroll
          for (int wl=0;wl<4;++wl){
            float x = xv[kd][wl+kw];
            #pragma unroll
            for (int o=0;o<8;++o)
              acc[o][wl] = fmaf(x, wp[o], acc[o][wl]);
          }
        }
      }
    }
  }

  float part = 0.f;
  const int lbase = d*(HH_*WW_) + h*WW_ + w0;
  #pragma unroll
  for (int wl=0;wl<4;++wl){
    int l = lbase + wl;
    #pragma unroll
    for (int o=0;o<NCLS;++o){
      float z = acc[o][wl] + cls_b[o];
      logits_ws[(size_t)(b*NCLS+o)*LL + l] = z;
      float pr = sigmoidf_(z);
      part += 0.75f*pr*pr*softplusf_(z);
    }
    float4 ctr;
    ctr.x = ((float)d+0.5f)*2.f      + acc[5][wl] + off_b[0];
    ctr.y = ((float)h+0.5f)*2.f      + acc[6][wl] + off_b[1];
    ctr.z = ((float)(w0+wl)+0.5f)*2.f+ acc[7][wl] + off_b[2];
    ctr.w = 0.f;
    *(float4*)(centers_ws + ((size_t)b*LL + l)*4) = ctr;
  }

  #pragma unroll
  for (int off=32;off;off>>=1) part += __shfl_down(part, off);
  __shared__ float wsum[4];
  int tid = ty*16 + tx;
  if ((tid & 63)==0) wsum[tid>>6] = part;
  __syncthreads();
  if (tid==0) atomicAdd(bg_sum, wsum[0]+wsum[1]+wsum[2]+wsum[3]);
}

// ---------------- Phase B: per-(b,n,segment) top-13 of align over L/SEG anchors
__global__ __launch_bounds__(256) void topk_partial_kernel(
    const float* __restrict__ logits_ws, const float* __restrict__ centers_ws,
    const float* __restrict__ labels,    // [B][32][5]
    float* __restrict__ pv, int* __restrict__ pi)  // [64][SEG][13]
{
  const int bn = blockIdx.x;           // 0..63
  const int seg = blockIdx.y;          // 0..SEG-1
  const int b = bn >> 5, n = bn & 31;
  const int tid = threadIdx.x;

  const float* lb = labels + (b*NMAXG + n)*5;
  const float tx = lb[0], ty = lb[1], tz = lb[2];
  const float cf = lb[3];
  const float sg = lb[4];
  const int lab = (cf == -100.f) ? 0 : (int)cf;
  const float m6 = -3.f/(sg*sg);

  const float* lg = logits_ws + (size_t)(b*NCLS + lab)*LL;
  const float* cb = centers_ws + (size_t)b*LL*4;

  float v[13]; int ix[13];
  #pragma unroll
  for (int j=0;j<13;++j){ v[j]=-1.f; ix[j]=0x7fffffff; }

  const int l0 = seg*SEGL;
  for (int l = l0 + tid; l < l0 + SEGL; l += 256){
    float4 c4 = *(const float4*)(cb + (size_t)l*4);
    float dx = c4.x-tx, dy = c4.y-ty, dz = c4.z-tz;
    float d2 = dx*dx + dy*dy + dz*dz;
    float a = sigmoidf_(lg[l]) * expf(m6*d2);
    if (a > v[12]){
      float cv = a; int ci = l;
      #pragma unroll
      for (int j=0;j<13;++j){
        bool take = (cv > v[j]) || (cv == v[j] && ci < ix[j]);
        float nv = take ? cv : v[j];  float ov = take ? v[j] : cv;
        int   ni = take ? ci : ix[j]; int   oi = take ? ix[j] : ci;
        v[j]=nv; ix[j]=ni; cv=ov; ci=oi;
      }
    }
  }

  __shared__ float sv[256*13];
  __shared__ int   si[256*13];
  #pragma unroll
  for (int j=0;j<13;++j){ sv[tid*13+j]=v[j]; si[tid*13+j]=ix[j]; }
  __syncthreads();
  __shared__ float rv[256]; __shared__ int ri[256]; __shared__ int rs[256];
  for (int k=0;k<13;++k){
    float bv=-2.f; int bi=0x7fffffff; int bs=-1;
    #pragma unroll
    for (int j=0;j<13;++j){
      float x = sv[tid*13+j]; int xi = si[tid*13+j];
      if (x>bv || (x==bv && xi<bi)){ bv=x; bi=xi; bs=tid*13+j; }
    }
    rv[tid]=bv; ri[tid]=bi; rs[tid]=bs;
    __syncthreads();
    for (int s2=128;s2;s2>>=1){
      if (tid<s2){
        if (rv[tid+s2]>rv[tid] || (rv[tid+s2]==rv[tid] && ri[tid+s2]<ri[tid])){
          rv[tid]=rv[tid+s2]; ri[tid]=ri[tid+s2]; rs[tid]=rs[tid+s2];
        }
      }
      __syncthreads();
    }
    if (tid==0){
      pv[(bn*SEG+seg)*TOPKK + k] = rv[0];
      pi[(bn*SEG+seg)*TOPKK + k] = ri[0];
      if (rs[0]>=0) sv[rs[0]] = -2.f;
    }
    __syncthreads();
  }
}

// ---------------- Phase B2: merge SEG partial top-13s -> global top-13 per (b,n)
__global__ __launch_bounds__(256) void topk_merge_kernel(
    const float* __restrict__ pv, const int* __restrict__ pi,
    float* __restrict__ tv, int* __restrict__ ti)
{
  const int bn = blockIdx.x;
  const int t = threadIdx.x;       // 256
  const int NC = SEG*TOPKK;        // 208
  float v = -2.f; int ix = 0x7fffffff;
  if (t < NC){ v = pv[bn*NC + t]; ix = pi[bn*NC + t]; }
  __shared__ float sv[256]; __shared__ int si[256]; __shared__ int sl[256];
  for (int k=0;k<13;++k){
    sv[t]=v; si[t]=ix; sl[t]=t;
    __syncthreads();
    for (int s2=128;s2;s2>>=1){
      if (t<s2){
        if (sv[t+s2]>sv[t] || (sv[t+s2]==sv[t] && si[t+s2]<si[t])){
          sv[t]=sv[t+s2]; si[t]=si[t+s2]; sl[t]=sl[t+s2];
        }
      }
      __syncthreads();
    }
    if (t==0){ tv[bn*TOPKK+k]=sv[0]; ti[bn*TOPKK+k]=si[0]; }
    int win = sl[0];
    __syncthreads();
    if (t==win) v = -2.f;
  }
}

// ---------------- Phase C: candidate resolution + corrections + reg loss + final scalar
__global__ __launch_bounds__(256) void finalize_kernel(
    const float* __restrict__ logits_ws, const float* __restrict__ centers_ws,
    const float* __restrict__ labels,
    const float* __restrict__ tv, const int* __restrict__ ti,
    const float* __restrict__ bg_sum, float* __restrict__ out)
{
  const int tid = threadIdx.x;   // 256
  __shared__ float gx[32], gy[32], gz[32], gs[32];
  __shared__ int glab[32], gvalid[32];
  __shared__ int   ent_l[416];
  __shared__ int   ent_ok[416];
  __shared__ int   ent_first[416];
  __shared__ int   ent_n[416];
  __shared__ float ent_a[416], ent_i[416];
  __shared__ unsigned maxA[32], maxI[32];
  __shared__ float accD, accC;
  if (tid==0){ accD=0.f; accC=0.f; }

  for (int b=0;b<NB;++b){
    if (tid<32){
      const float* lb = labels + (b*NMAXG + tid)*5;
      gx[tid]=lb[0]; gy[tid]=lb[1]; gz[tid]=lb[2];
      float cf = lb[3]; gs[tid]=lb[4];
      int val = (cf != -100.f);
      gvalid[tid]=val; glab[tid]= val ? (int)cf : 0;
      maxA[tid]=0u; maxI[tid]=0u;
    }
    __syncthreads();
    for (int e=tid;e<416;e+=256){
      int n = e/13, k = e - 13*n;
      float v = tv[(b*NMAXG+n)*TOPKK + k];
      ent_l[e]  = ti[(b*NMAXG+n)*TOPKK + k];
      ent_ok[e] = gvalid[n] && (v > 1e-9f);
      ent_first[e]=0; ent_n[e]=-1; ent_a[e]=0.f; ent_i[e]=0.f;
    }
    __syncthreads();
    for (int e=tid;e<416;e+=256){
      if (!ent_ok[e]) continue;
      int l = ent_l[e]; int cnt=0; int first=1;
      for (int e2=0;e2<416;++e2){
        if (ent_ok[e2] && ent_l[e2]==l){ cnt++; if (e2<e) first=0; }
      }
      if (!first) continue;
      ent_first[e]=1;
      float px = centers_ws[((size_t)b*LL + l)*4 + 0];
      float py = centers_ws[((size_t)b*LL + l)*4 + 1];
      float pz = centers_ws[((size_t)b*LL + l)*4 + 2];
      int nstar;
      if (cnt==1){
        nstar = e/13;
      } else {
        float best = -1.f; int bidx = 0;
        for (int nn=0;nn<32;++nn){
          float dx=gx[nn]-px, dy=gy[nn]-py, dz=gz[nn]-pz;
          float d2 = dx*dx+dy*dy+dz*dz;
          float iou = expf(-d2/(2.f*gs[nn]*gs[nn]));
          if (iou > best){ best=iou; bidx=nn; }
        }
        nstar = bidx;
      }
      ent_n[e] = nstar;
      float dx=gx[nstar]-px, dy=gy[nstar]-py, dz=gz[nstar]-pz;
      float d2 = dx*dx+dy*dy+dz*dz;
      float sgv = gs[nstar];
      float iou = expf(-d2/(2.f*sgv*sgv));
      float z = logits_ws[(size_t)(b*NCLS + glab[nstar])*LL + l];
      float a = sigmoidf_(z) * expf(-3.f*d2/(sgv*sgv));
      ent_a[e]=a; ent_i[e]=iou;
      atomicMax(&maxA[nstar], __float_as_uint(a));
      atomicMax(&maxI[nstar], __float_as_uint(iou));
    }
    __syncthreads();
    for (int e=tid;e<416;e+=256){
      if (!ent_first[e]) continue;
      int l = ent_l[e]; int nstar = ent_n[e];
      float mA = __uint_as_float(maxA[nstar]);
      float mI = __uint_as_float(maxI[nstar]);
      float score = ent_a[e]*mI/(mA + 1e-9f);
      int lab = glab[nstar];
      float z = logits_ws[(size_t)(b*NCLS + lab)*LL + l];
      float p = sigmoidf_(z);
      float t2 = log1pf(expf(-fabsf(z)));
      float spz = fmaxf(z,0.f) + t2;
      float spm = fmaxf(-z,0.f) + t2;
      float corr = score*(score*spm + (1.f-score)*spz) - 0.75f*p*p*spz;
      float reg  = (1.f - ent_i[e])*score;
      atomicAdd(&accD, score);
      atomicAdd(&accC, corr + reg);
    }
    __syncthreads();
  }
  if (tid==0) out[0] = (bg_sum[0] + accC) / accD;
}

extern "C" void kernel_launch(void* const* d_in, const int* in_sizes, int n_in,
                              void* d_out, int out_size, void* d_ws, size_t ws_size,
                              hipStream_t stream) {
  const float* feat  = (const float*)d_in[0];
  const float* cls_w = (const float*)d_in[1];
  const float* cls_b = (const float*)d_in[2];
  const float* off_w = (const float*)d_in[3];
  const float* off_b = (const float*)d_in[4];
  const float* labels= (const float*)d_in[5];
  float* out = (float*)d_out;

  float* logits_ws  = (float*)d_ws;                              // 2*5*L
  float* centers_ws = logits_ws + (size_t)NB*NCLS*LL;            // 2*L*4
  float* pv = centers_ws + (size_t)NB*LL*4;                      // 64*SEG*13
  int*   pi = (int*)(pv + 64*SEG*TOPKK);
  float* tv = (float*)(pi + 64*SEG*TOPKK);                       // 64*13
  int*   ti = (int*)(tv + 64*TOPKK);
  float* bg = (float*)(ti + 64*TOPKK);                           // 1
  float* wT = bg + 16;                                           // 64*27*8

  hipMemsetAsync(bg, 0, sizeof(float), stream);

  wtrans_kernel<<<1, 256, 0, stream>>>(cls_w, off_w, wT);
  conv_loss_kernel<<<dim3(4,64,2), dim3(16,16,1), 0, stream>>>(
      feat, wT, cls_b, off_b, logits_ws, centers_ws, bg);
  topk_partial_kernel<<<dim3(64,SEG), 256, 0, stream>>>(
      logits_ws, centers_ws, labels, pv, pi);
  topk_merge_kernel<<<64, 256, 0, stream>>>(pv, pi, tv, ti);
  finalize_kernel<<<1, 256, 0, stream>>>(
      logits_ws, centers_ws, labels, tv, ti, bg, out);
}

// Round 3
// 363.039 us; speedup vs baseline: 2.9000x; 1.4006x over previous
//
#include <hip/hip_runtime.h>
#include <math.h>

#define NB 2
#define CIN 64
#define DD_ 64
#define HH_ 64
#define WW_ 64
#define NCLS 5
#define LL (DD_*HH_*WW_)   /* 262144 */
#define NMAXG 32
#define TOPKK 13
#define SEG 16
#define SEGL (LL/SEG)      /* 16384 */

typedef __attribute__((ext_vector_type(8))) short short8b;
typedef __attribute__((ext_vector_type(4))) float floatx4;

__device__ __forceinline__ float softplusf_(float z){
  return fmaxf(z, 0.f) + log1pf(expf(-fabsf(z)));
}
__device__ __forceinline__ float sigmoidf_(float z){
  return 1.f/(1.f + expf(-z));
}
__device__ __forceinline__ short tobf_(float f){
  unsigned u = __float_as_uint(f);
  unsigned r = (u + 0x7fffu + ((u>>16)&1u)) >> 16;
  return (short)r;
}

// ---------------- Phase 0: build MFMA A-fragments from weights
// wA[slice][lane][i] bf16; slice = ((kd*3+kw)*2+s)*4 + cc  (72 slices)
// A[m][k]: m=outch (8 used), k = khl*16 + c_local; s=0: kh=khl(0,1); s=1: khl0->kh2, khl1->zero
__global__ __launch_bounds__(256) void wtrans_kernel(
    const float* __restrict__ cls_w, const float* __restrict__ off_w,
    short* __restrict__ wA)
{
  int idx = blockIdx.x*256 + threadIdx.x;
  if (idx >= 72*64) return;
  int slice = idx >> 6; int lane = idx & 63;
  int cc = slice & 3; int r = slice >> 2;
  int s  = r & 1;     int kk = r >> 1;
  int kd = kk/3, kw = kk - 3*(kk/3);
  int m = lane & 15, g = lane >> 4;
  short8b out;
  #pragma unroll
  for (int i=0;i<8;++i){
    int k = g*8 + i; int khl = k >> 4; int cl = k & 15;
    int kh = (s==0) ? khl : (khl==0 ? 2 : -1);
    float wv = 0.f;
    if (m < 8 && kh >= 0){
      int c = cc*16 + cl;
      if (m < NCLS) wv = cls_w[(m*CIN + c)*27 + (kd*3+kh)*3 + kw];
      else          wv = off_w[((m-NCLS)*CIN + c)*27 + (kd*3+kh)*3 + kw];
    }
    out[i] = tobf_(wv);
  }
  *(short8b*)(wA + (size_t)idx*8) = out;
}

// ---------------- Phase A: MFMA conv. Block: 4d x 4h x 64w outputs, 8 ch. 512 thr.
__global__ __launch_bounds__(512, 4) void conv_mfma_kernel(
    const float* __restrict__ feat,
    const short* __restrict__ wA,
    const float* __restrict__ cls_b, const float* __restrict__ off_b,
    float* __restrict__ logits_ws,   // [B][5][L]
    float* __restrict__ centers_ws,  // [B][L][4]
    float* __restrict__ bg_sum)
{
  __shared__ short xs[36*68*16];     // [row=6d'*6h'][wp 0..67][16c] bf16, 78336 B
  __shared__ float bsum[8];

  const int tid = threadIdx.x;
  const int lane = tid & 63, wv = tid >> 6;
  const int col = lane & 15, g = lane >> 4;
  const int chalf = g & 1, khl = g >> 1;
  const int h0 = blockIdx.x*4, d0 = blockIdx.y*4, b = blockIdx.z;

  // zero the w-halo slots (wp 0 and 65) once
  for (int idx = tid; idx < 36*32; idx += 512){
    int row = idx >> 5; int rr = idx & 31;
    int wp = (rr < 16) ? 0 : 65;
    xs[(row*68 + wp)*16 + (rr & 15)] = 0;
  }

  floatx4 acc[8];
  #pragma unroll
  for (int t=0;t<8;++t) acc[t] = (floatx4){0.f,0.f,0.f,0.f};

  const short8b* wAv = (const short8b*)wA;

  for (int cc=0; cc<4; ++cc){
    if (cc) __syncthreads();   // prev compute done before overwrite
    // ---- stage chunk: 16c x 36 rows x 64w fp32 -> bf16 LDS
    #pragma unroll 1
    for (int it=0; it<18; ++it){
      int idx = it*512 + tid;            // 0..9215
      int ci  = idx / 576;
      int rem = idx - ci*576;
      int row = rem >> 4;
      int w4  = rem & 15;
      int row_d = row/6;
      int row_h = row - row_d*6;
      int d_ = d0 - 1 + row_d;
      int h_ = h0 - 1 + row_h;
      float4 x = make_float4(0.f,0.f,0.f,0.f);
      if (d_ >= 0 && d_ < DD_ && h_ >= 0 && h_ < HH_){
        const float* p = feat + ((((size_t)b*CIN + cc*16 + ci)*DD_ + d_)*HH_ + h_)*WW_ + w4*4;
        x = *(const float4*)p;
      }
      int base = row*68*16;
      #pragma unroll
      for (int j=0;j<4;++j){
        int wp = w4*4 + j + 1;
        float xv = (j==0)?x.x:((j==1)?x.y:((j==2)?x.z:x.w));
        int sw = (ci>>3) ^ ((wp>>2)&1);
        xs[base + wp*16 + (ci&7) + (sw<<3)] = tobf_(xv);
      }
    }
    __syncthreads();
    // ---- compute: 18 K-slices x 8 tiles per wave
    #pragma unroll 1
    for (int kk=0; kk<9; ++kk){         // kd*3+kw
      int kd = kk/3, kw = kk - 3*(kd);
      #pragma unroll
      for (int s=0;s<2;++s){
        int slice = (kk*2 + s)*4 + cc;
        short8b a = wAv[slice*64 + lane];
        int khe = s ? 2 : khl;
        #pragma unroll
        for (int t=0;t<8;++t){
          int tile = wv*8 + t;
          int dl = tile>>4, hl = (tile>>2)&3, wq = tile&3;
          int row = (dl+kd)*6 + hl + khe;
          int wp = wq*16 + col + kw;
          int sidx = (row*68 + wp)*16 + ((chalf ^ ((wp>>2)&1))<<3);
          short8b bfr = *(const short8b*)(xs + sidx);
          acc[t] = __builtin_amdgcn_mfma_f32_16x16x32_bf16(a, bfr, acc[t], 0,0,0);
        }
      }
    }
  }

  // ---- epilogue
  float bg = 0.f;
  #pragma unroll
  for (int t=0;t<8;++t){
    int tile = wv*8 + t;
    int dl = tile>>4, hl = (tile>>2)&3, wq = tile&3;
    int d = d0+dl, h = h0+hl, w = wq*16 + col;
    size_t l = (size_t)d*4096 + (size_t)h*64 + w;
    if (g == 0){
      #pragma unroll
      for (int j=0;j<4;++j){
        float z = acc[t][j] + cls_b[j];
        logits_ws[(size_t)(b*NCLS+j)*LL + l] = z;
        float pr = sigmoidf_(z);
        bg += 0.75f*pr*pr*softplusf_(z);
      }
    } else if (g == 1){
      float z = acc[t][0] + cls_b[4];
      logits_ws[(size_t)(b*NCLS+4)*LL + l] = z;
      float pr = sigmoidf_(z);
      bg += 0.75f*pr*pr*softplusf_(z);
      float4 ctr;
      ctr.x = ((float)d+0.5f)*2.f + acc[t][1] + off_b[0];
      ctr.y = ((float)h+0.5f)*2.f + acc[t][2] + off_b[1];
      ctr.z = ((float)w+0.5f)*2.f + acc[t][3] + off_b[2];
      ctr.w = 0.f;
      *(float4*)(centers_ws + ((size_t)b*LL + l)*4) = ctr;
    }
  }
  #pragma unroll
  for (int off=32;off;off>>=1) bg += __shfl_down(bg, off);
  if (lane == 0) bsum[wv] = bg;
  __syncthreads();
  if (tid == 0){
    float s = 0.f;
    #pragma unroll
    for (int i=0;i<8;++i) s += bsum[i];
    atomicAdd(bg_sum, s);
  }
}

// ---------------- Phase B: per-(b,n,segment) top-13 of align
__global__ __launch_bounds__(256) void topk_partial_kernel(
    const float* __restrict__ logits_ws, const float* __restrict__ centers_ws,
    const float* __restrict__ labels,
    float* __restrict__ pv, int* __restrict__ pi)  // [64][SEG][13]
{
  const int bn = blockIdx.x;
  const int seg = blockIdx.y;
  const int b = bn >> 5, n = bn & 31;
  const int tid = threadIdx.x;

  const float* lb = labels + (b*NMAXG + n)*5;
  const float tx = lb[0], ty = lb[1], tz = lb[2];
  const float cf = lb[3];
  const float sg = lb[4];
  const int lab = (cf == -100.f) ? 0 : (int)cf;
  const float m6 = -3.f/(sg*sg);

  const float* lg = logits_ws + (size_t)(b*NCLS + lab)*LL;
  const float* cb = centers_ws + (size_t)b*LL*4;

  float v[13]; int ix[13];
  #pragma unroll
  for (int j=0;j<13;++j){ v[j]=-1.f; ix[j]=0x7fffffff; }

  const int l0 = seg*SEGL;
  for (int l = l0 + tid; l < l0 + SEGL; l += 256){
    float4 c4 = *(const float4*)(cb + (size_t)l*4);
    float dx = c4.x-tx, dy = c4.y-ty, dz = c4.z-tz;
    float e = m6*(dx*dx + dy*dy + dz*dz);
    if (e < -20.8f) continue;            // align < 1e-9 -> dropped by EPS gate anyway
    float a = sigmoidf_(lg[l]) * expf(e);
    if (a > v[12]){
      float cv = a; int ci = l;
      #pragma unroll
      for (int j=0;j<13;++j){
        bool take = (cv > v[j]) || (cv == v[j] && ci < ix[j]);
        float nv = take ? cv : v[j];  float ov = take ? v[j] : cv;
        int   ni = take ? ci : ix[j]; int   oi = take ? ix[j] : ci;
        v[j]=nv; ix[j]=ni; cv=ov; ci=oi;
      }
    }
  }

  // wave merge: 13 butterfly-pop rounds
  const int lane = tid & 63, wvi = tid >> 6;
  float mv = -2.f; int mi = 0x7fffffff;
  #pragma unroll 1
  for (int k=0;k<13;++k){
    float bv = v[0]; int bi = ix[0]; int bl = lane;
    #pragma unroll
    for (int off=32; off; off>>=1){
      float ov2 = __shfl_xor(bv, off);
      int oi = __shfl_xor(bi, off);
      int ol = __shfl_xor(bl, off);
      if (ov2 > bv || (ov2 == bv && oi < bi)){ bv=ov2; bi=oi; bl=ol; }
    }
    if (lane == k){ mv = bv; mi = bi; }
    if (lane == bl){
      #pragma unroll
      for (int j=0;j<12;++j){ v[j]=v[j+1]; ix[j]=ix[j+1]; }
      v[12] = -2.f; ix[12] = 0x7fffffff;
    }
  }
  __shared__ float sv2[4*13]; __shared__ int si2[4*13];
  if (lane < 13){ sv2[wvi*13+lane] = mv; si2[wvi*13+lane] = mi; }
  __syncthreads();
  if (wvi == 0){
    float v2 = -2.f; int i2 = 0x7fffffff;
    if (lane < 52){ v2 = sv2[lane]; i2 = si2[lane]; }
    #pragma unroll 1
    for (int k=0;k<13;++k){
      float bv = v2; int bi = i2; int bl = lane;
      #pragma unroll
      for (int off=32; off; off>>=1){
        float ov2 = __shfl_xor(bv, off);
        int oi = __shfl_xor(bi, off);
        int ol = __shfl_xor(bl, off);
        if (ov2 > bv || (ov2 == bv && oi < bi)){ bv=ov2; bi=oi; bl=ol; }
      }
      if (lane == 0){
        pv[(bn*SEG+seg)*TOPKK + k] = bv;
        pi[(bn*SEG+seg)*TOPKK + k] = bi;
      }
      if (lane == bl) v2 = -2.f;
    }
  }
}

// ---------------- Phase B2: merge SEG partial top-13s -> global top-13 per (b,n)
__global__ __launch_bounds__(256) void topk_merge_kernel(
    const float* __restrict__ pv, const int* __restrict__ pi,
    float* __restrict__ tv, int* __restrict__ ti)
{
  const int bn = blockIdx.x;
  const int t = threadIdx.x;
  const int NC = SEG*TOPKK;        // 208
  float v = -2.f; int ix = 0x7fffffff;
  if (t < NC){ v = pv[bn*NC + t]; ix = pi[bn*NC + t]; }
  __shared__ float sv[256]; __shared__ int si[256]; __shared__ int sl[256];
  for (int k=0;k<13;++k){
    sv[t]=v; si[t]=ix; sl[t]=t;
    __syncthreads();
    for (int s2=128;s2;s2>>=1){
      if (t<s2){
        if (sv[t+s2]>sv[t] || (sv[t+s2]==sv[t] && si[t+s2]<si[t])){
          sv[t]=sv[t+s2]; si[t]=si[t+s2]; sl[t]=sl[t+s2];
        }
      }
      __syncthreads();
    }
    if (t==0){ tv[bn*TOPKK+k]=sv[0]; ti[bn*TOPKK+k]=si[0]; }
    int win = sl[0];
    __syncthreads();
    if (t==win) v = -2.f;
  }
}

// ---------------- Phase C: candidate resolution + corrections + reg loss + final
__global__ __launch_bounds__(256) void finalize_kernel(
    const float* __restrict__ logits_ws, const float* __restrict__ centers_ws,
    const float* __restrict__ labels,
    const float* __restrict__ tv, const int* __restrict__ ti,
    const float* __restrict__ bg_sum, float* __restrict__ out)
{
  const int tid = threadIdx.x;
  __shared__ float gx[32], gy[32], gz[32], gs[32];
  __shared__ int glab[32], gvalid[32];
  __shared__ int   ent_l[416];
  __shared__ int   ent_ok[416];
  __shared__ int   ent_first[416];
  __shared__ int   ent_n[416];
  __shared__ float ent_a[416], ent_i[416];
  __shared__ unsigned maxA[32], maxI[32];
  __shared__ float accD, accC;
  if (tid==0){ accD=0.f; accC=0.f; }

  for (int b=0;b<NB;++b){
    if (tid<32){
      const float* lb = labels + (b*NMAXG + tid)*5;
      gx[tid]=lb[0]; gy[tid]=lb[1]; gz[tid]=lb[2];
      float cf = lb[3]; gs[tid]=lb[4];
      int val = (cf != -100.f);
      gvalid[tid]=val; glab[tid]= val ? (int)cf : 0;
      maxA[tid]=0u; maxI[tid]=0u;
    }
    __syncthreads();
    for (int e=tid;e<416;e+=256){
      int n = e/13, k = e - 13*n;
      float v = tv[(b*NMAXG+n)*TOPKK + k];
      ent_l[e]  = ti[(b*NMAXG+n)*TOPKK + k];
      ent_ok[e] = gvalid[n] && (v > 1e-9f);
      ent_first[e]=0; ent_n[e]=-1; ent_a[e]=0.f; ent_i[e]=0.f;
    }
    __syncthreads();
    for (int e=tid;e<416;e+=256){
      if (!ent_ok[e]) continue;
      int l = ent_l[e]; int cnt=0; int first=1;
      for (int e2=0;e2<416;++e2){
        if (ent_ok[e2] && ent_l[e2]==l){ cnt++; if (e2<e) first=0; }
      }
      if (!first) continue;
      ent_first[e]=1;
      float px = centers_ws[((size_t)b*LL + l)*4 + 0];
      float py = centers_ws[((size_t)b*LL + l)*4 + 1];
      float pz = centers_ws[((size_t)b*LL + l)*4 + 2];
      int nstar;
      if (cnt==1){
        nstar = e/13;
      } else {
        float best = -1.f; int bidx = 0;
        for (int nn=0;nn<32;++nn){
          float dx=gx[nn]-px, dy=gy[nn]-py, dz=gz[nn]-pz;
          float d2 = dx*dx+dy*dy+dz*dz;
          float iou = expf(-d2/(2.f*gs[nn]*gs[nn]));
          if (iou > best){ best=iou; bidx=nn; }
        }
        nstar = bidx;
      }
      ent_n[e] = nstar;
      float dx=gx[nstar]-px, dy=gy[nstar]-py, dz=gz[nstar]-pz;
      float d2 = dx*dx+dy*dy+dz*dz;
      float sgv = gs[nstar];
      float iou = expf(-d2/(2.f*sgv*sgv));
      float z = logits_ws[(size_t)(b*NCLS + glab[nstar])*LL + l];
      float a = sigmoidf_(z) * expf(-3.f*d2/(sgv*sgv));
      ent_a[e]=a; ent_i[e]=iou;
      atomicMax(&maxA[nstar], __float_as_uint(a));
      atomicMax(&maxI[nstar], __float_as_uint(iou));
    }
    __syncthreads();
    for (int e=tid;e<416;e+=256){
      if (!ent_first[e]) continue;
      int l = ent_l[e]; int nstar = ent_n[e];
      float mA = __uint_as_float(maxA[nstar]);
      float mI = __uint_as_float(maxI[nstar]);
      float score = ent_a[e]*mI/(mA + 1e-9f);
      int lab = glab[nstar];
      float z = logits_ws[(size_t)(b*NCLS + lab)*LL + l];
      float p = sigmoidf_(z);
      float t2 = log1pf(expf(-fabsf(z)));
      float spz = fmaxf(z,0.f) + t2;
      float spm = fmaxf(-z,0.f) + t2;
      float corr = score*(score*spm + (1.f-score)*spz) - 0.75f*p*p*spz;
      float reg  = (1.f - ent_i[e])*score;
      atomicAdd(&accD, score);
      atomicAdd(&accC, corr + reg);
    }
    __syncthreads();
  }
  if (tid==0) out[0] = (bg_sum[0] + accC) / accD;
}

extern "C" void kernel_launch(void* const* d_in, const int* in_sizes, int n_in,
                              void* d_out, int out_size, void* d_ws, size_t ws_size,
                              hipStream_t stream) {
  const float* feat  = (const float*)d_in[0];
  const float* cls_w = (const float*)d_in[1];
  const float* cls_b = (const float*)d_in[2];
  const float* off_w = (const float*)d_in[3];
  const float* off_b = (const float*)d_in[4];
  const float* labels= (const float*)d_in[5];
  float* out = (float*)d_out;

  float* logits_ws  = (float*)d_ws;                              // 2*5*L
  float* centers_ws = logits_ws + (size_t)NB*NCLS*LL;            // 2*L*4
  float* pv = centers_ws + (size_t)NB*LL*4;                      // 64*SEG*13
  int*   pi = (int*)(pv + 64*SEG*TOPKK);
  float* tv = (float*)(pi + 64*SEG*TOPKK);                       // 64*13
  int*   ti = (int*)(tv + 64*TOPKK);
  float* bg = (float*)(ti + 64*TOPKK);                           // +16 pad
  short* wA = (short*)(bg + 16);                                 // 72*64*8 bf16

  hipMemsetAsync(bg, 0, sizeof(float), stream);

  wtrans_kernel<<<18, 256, 0, stream>>>(cls_w, off_w, wA);
  conv_mfma_kernel<<<dim3(16,16,2), 512, 0, stream>>>(
      feat, wA, cls_b, off_b, logits_ws, centers_ws, bg);
  topk_partial_kernel<<<dim3(64,SEG), 256, 0, stream>>>(
      logits_ws, centers_ws, labels, pv, pi);
  topk_merge_kernel<<<64, 256, 0, stream>>>(pv, pi, tv, ti);
  finalize_kernel<<<1, 256, 0, stream>>>(
      logits_ws, centers_ws, labels, tv, ti, bg, out);
}

// Round 4
// 202.681 us; speedup vs baseline: 5.1944x; 1.7912x over previous
//
#include <hip/hip_runtime.h>
#include <math.h>

#define NB 2
#define CIN 64
#define DD_ 64
#define HH_ 64
#define WW_ 64
#define NCLS 5
#define LL (DD_*HH_*WW_)   /* 262144 */
#define NMAXG 32
#define TOPKK 13
#define SEG 16
#define SEGL (LL/SEG)      /* 16384 */

typedef __attribute__((ext_vector_type(8))) short short8b;
typedef __attribute__((ext_vector_type(4))) float floatx4;

__device__ __forceinline__ float softplusf_(float z){
  return fmaxf(z, 0.f) + log1pf(expf(-fabsf(z)));
}
__device__ __forceinline__ float sigmoidf_(float z){
  return 1.f/(1.f + expf(-z));
}
__device__ __forceinline__ unsigned tobf_u_(float f){
  unsigned u = __float_as_uint(f);
  return (u + 0x7fffu + ((u>>16)&1u)) >> 16;
}
__device__ __forceinline__ short tobf_(float f){
  return (short)tobf_u_(f);
}

// ---------------- Phase 0: build MFMA A-fragments from weights
__global__ __launch_bounds__(256) void wtrans_kernel(
    const float* __restrict__ cls_w, const float* __restrict__ off_w,
    short* __restrict__ wA)
{
  int idx = blockIdx.x*256 + threadIdx.x;
  if (idx >= 72*64) return;
  int slice = idx >> 6; int lane = idx & 63;
  int cc = slice & 3; int r = slice >> 2;
  int s  = r & 1;     int kk = r >> 1;
  int kd = kk/3, kw = kk - 3*(kk/3);
  int m = lane & 15, g = lane >> 4;
  short8b out;
  #pragma unroll
  for (int i=0;i<8;++i){
    int k = g*8 + i; int khl = k >> 4; int cl = k & 15;
    int kh = (s==0) ? khl : (khl==0 ? 2 : -1);
    float wv = 0.f;
    if (m < 8 && kh >= 0){
      int c = cc*16 + cl;
      if (m < NCLS) wv = cls_w[(m*CIN + c)*27 + (kd*3+kh)*3 + kw];
      else          wv = off_w[((m-NCLS)*CIN + c)*27 + (kd*3+kh)*3 + kw];
    }
    out[i] = tobf_(wv);
  }
  *(short8b*)(wA + (size_t)idx*8) = out;
}

// ---------------- Phase A: MFMA conv. Block: 4d x 4h x 64w outputs, 8 ch. 512 thr.
__global__ __launch_bounds__(512, 4) void conv_mfma_kernel(
    const float* __restrict__ feat,
    const short* __restrict__ wA,
    const float* __restrict__ cls_b, const float* __restrict__ off_b,
    float* __restrict__ logits_ws,   // [B][5][L]
    float* __restrict__ centers_ws,  // [B][L][4]
    float* __restrict__ bg_sum)
{
  __shared__ short xs[36*68*16];     // [row=6d'*6h'][wp 0..67][16c] bf16, 78336 B
  __shared__ float bsum[8];

  const int tid = threadIdx.x;
  const int lane = tid & 63, wv = tid >> 6;
  const int col = lane & 15, g = lane >> 4;
  const int chalf = g & 1, khl = g >> 1;
  const int h0 = blockIdx.x*4, d0 = blockIdx.y*4, b = blockIdx.z;

  // zero the w-halo slots (wp 0 and 65) once
  for (int idx = tid; idx < 36*32; idx += 512){
    int row = idx >> 5; int rr = idx & 31;
    int wp = (rr < 16) ? 0 : 65;
    xs[(row*68 + wp)*16 + (rr & 15)] = 0;
  }

  floatx4 acc[8];
  #pragma unroll
  for (int t=0;t<8;++t) acc[t] = (floatx4){0.f,0.f,0.f,0.f};

  const short8b* wAv = (const short8b*)wA;

  for (int cc=0; cc<4; ++cc){
    if (cc) __syncthreads();   // prev compute done before overwrite
    // ---- stage chunk: 8 channel-pairs x 36 rows x 64w fp32 -> packed bf16x2 LDS
    #pragma unroll 1
    for (int it=0; it<9; ++it){
      int idx = it*512 + tid;            // 0..4607
      int p   = idx / 576;               // channel pair 0..7 (c = 2p, 2p+1)
      int rem = idx - p*576;
      int row = rem >> 4;
      int w4  = rem & 15;
      int row_d = row/6;
      int row_h = row - row_d*6;
      int d_ = d0 - 1 + row_d;
      int h_ = h0 - 1 + row_h;
      float4 x0 = make_float4(0.f,0.f,0.f,0.f);
      float4 x1 = x0;
      if (d_ >= 0 && d_ < DD_ && h_ >= 0 && h_ < HH_){
        const float* pp = feat + ((((size_t)b*CIN + cc*16 + 2*p)*DD_ + d_)*HH_ + h_)*WW_ + w4*4;
        x0 = *(const float4*)pp;
        x1 = *(const float4*)(pp + LL);
      }
      int base = row*68*16 + ((2*p)&7);
      int swp  = p>>2;
      #pragma unroll
      for (int j=0;j<4;++j){
        int wp = w4*4 + j + 1;
        float a0 = (j==0)?x0.x:((j==1)?x0.y:((j==2)?x0.z:x0.w));
        float a1 = (j==0)?x1.x:((j==1)?x1.y:((j==2)?x1.z:x1.w));
        unsigned pk = (tobf_u_(a1)<<16) | tobf_u_(a0);
        int sw = swp ^ ((wp>>2)&1);
        *(unsigned*)(xs + base + wp*16 + (sw<<3)) = pk;
      }
    }
    __syncthreads();
    // ---- compute: 18 K-slices x 8 tiles per wave
    #pragma unroll 1
    for (int kk=0; kk<9; ++kk){         // kd*3+kw
      int kd = kk/3, kw = kk - 3*(kd);
      #pragma unroll
      for (int s=0;s<2;++s){
        int slice = (kk*2 + s)*4 + cc;
        short8b a = wAv[slice*64 + lane];
        int khe = s ? 2 : khl;
        #pragma unroll
        for (int t=0;t<8;++t){
          int tile = wv*8 + t;
          int dl = tile>>4, hl = (tile>>2)&3, wq = tile&3;
          int row = (dl+kd)*6 + hl + khe;
          int wp = wq*16 + col + kw;
          int sidx = (row*68 + wp)*16 + ((chalf ^ ((wp>>2)&1))<<3);
          short8b bfr = *(const short8b*)(xs + sidx);
          acc[t] = __builtin_amdgcn_mfma_f32_16x16x32_bf16(a, bfr, acc[t], 0,0,0);
        }
      }
    }
  }

  // ---- epilogue
  float bg = 0.f;
  #pragma unroll
  for (int t=0;t<8;++t){
    int tile = wv*8 + t;
    int dl = tile>>4, hl = (tile>>2)&3, wq = tile&3;
    int d = d0+dl, h = h0+hl, w = wq*16 + col;
    size_t l = (size_t)d*4096 + (size_t)h*64 + w;
    if (g == 0){
      #pragma unroll
      for (int j=0;j<4;++j){
        float z = acc[t][j] + cls_b[j];
        logits_ws[(size_t)(b*NCLS+j)*LL + l] = z;
        float pr = sigmoidf_(z);
        bg += 0.75f*pr*pr*softplusf_(z);
      }
    } else if (g == 1){
      float z = acc[t][0] + cls_b[4];
      logits_ws[(size_t)(b*NCLS+4)*LL + l] = z;
      float pr = sigmoidf_(z);
      bg += 0.75f*pr*pr*softplusf_(z);
      float4 ctr;
      ctr.x = ((float)d+0.5f)*2.f + acc[t][1] + off_b[0];
      ctr.y = ((float)h+0.5f)*2.f + acc[t][2] + off_b[1];
      ctr.z = ((float)w+0.5f)*2.f + acc[t][3] + off_b[2];
      ctr.w = 0.f;
      *(float4*)(centers_ws + ((size_t)b*LL + l)*4) = ctr;
    }
  }
  #pragma unroll
  for (int off=32;off;off>>=1) bg += __shfl_down(bg, off);
  if (lane == 0) bsum[wv] = bg;
  __syncthreads();
  if (tid == 0){
    float s = 0.f;
    #pragma unroll
    for (int i=0;i<8;++i) s += bsum[i];
    atomicAdd(bg_sum, s);
  }
}

// ---------------- Phase B: per-(b,n,segment) top-13 of align
__global__ __launch_bounds__(256) void topk_partial_kernel(
    const float* __restrict__ logits_ws, const float* __restrict__ centers_ws,
    const float* __restrict__ labels,
    float* __restrict__ pv, int* __restrict__ pi)  // [64][SEG][13]
{
  const int bn = blockIdx.x;
  const int seg = blockIdx.y;
  const int b = bn >> 5, n = bn & 31;
  const int tid = threadIdx.x;

  const float* lb = labels + (b*NMAXG + n)*5;
  const float tx = lb[0], ty = lb[1], tz = lb[2];
  const float cf = lb[3];
  const float sg = lb[4];
  const int lab = (cf == -100.f) ? 0 : (int)cf;
  const float m6 = -3.f/(sg*sg);

  const float* lg = logits_ws + (size_t)(b*NCLS + lab)*LL;
  const float* cb = centers_ws + (size_t)b*LL*4;

  float v[13]; int ix[13];
  #pragma unroll
  for (int j=0;j<13;++j){ v[j]=-1.f; ix[j]=0x7fffffff; }

  const int l0 = seg*SEGL;
  for (int l = l0 + tid; l < l0 + SEGL; l += 256){
    float4 c4 = *(const float4*)(cb + (size_t)l*4);
    float dx = c4.x-tx, dy = c4.y-ty, dz = c4.z-tz;
    float e = m6*(dx*dx + dy*dy + dz*dz);
    if (e < -20.8f) continue;            // align < 1e-9 -> dropped by EPS gate anyway
    float a = sigmoidf_(lg[l]) * expf(e);
    if (a > v[12]){
      float cv = a; int ci = l;
      #pragma unroll
      for (int j=0;j<13;++j){
        bool take = (cv > v[j]) || (cv == v[j] && ci < ix[j]);
        float nv = take ? cv : v[j];  float ov = take ? v[j] : cv;
        int   ni = take ? ci : ix[j]; int   oi = take ? ix[j] : ci;
        v[j]=nv; ix[j]=ni; cv=ov; ci=oi;
      }
    }
  }

  // wave merge: 13 butterfly-pop rounds
  const int lane = tid & 63, wvi = tid >> 6;
  float mv = -2.f; int mi = 0x7fffffff;
  #pragma unroll 1
  for (int k=0;k<13;++k){
    float bv = v[0]; int bi = ix[0]; int bl = lane;
    #pragma unroll
    for (int off=32; off; off>>=1){
      float ov2 = __shfl_xor(bv, off);
      int oi = __shfl_xor(bi, off);
      int ol = __shfl_xor(bl, off);
      if (ov2 > bv || (ov2 == bv && oi < bi)){ bv=ov2; bi=oi; bl=ol; }
    }
    if (lane == k){ mv = bv; mi = bi; }
    if (lane == bl){
      #pragma unroll
      for (int j=0;j<12;++j){ v[j]=v[j+1]; ix[j]=ix[j+1]; }
      v[12] = -2.f; ix[12] = 0x7fffffff;
    }
  }
  __shared__ float sv2[4*13]; __shared__ int si2[4*13];
  if (lane < 13){ sv2[wvi*13+lane] = mv; si2[wvi*13+lane] = mi; }
  __syncthreads();
  if (wvi == 0){
    float v2 = -2.f; int i2 = 0x7fffffff;
    if (lane < 52){ v2 = sv2[lane]; i2 = si2[lane]; }
    #pragma unroll 1
    for (int k=0;k<13;++k){
      float bv = v2; int bi = i2; int bl = lane;
      #pragma unroll
      for (int off=32; off; off>>=1){
        float ov2 = __shfl_xor(bv, off);
        int oi = __shfl_xor(bi, off);
        int ol = __shfl_xor(bl, off);
        if (ov2 > bv || (ov2 == bv && oi < bi)){ bv=ov2; bi=oi; bl=ol; }
      }
      if (lane == 0){
        pv[(bn*SEG+seg)*TOPKK + k] = bv;
        pi[(bn*SEG+seg)*TOPKK + k] = bi;
      }
      if (lane == bl) v2 = -2.f;
    }
  }
}

// ---------------- Phase B2: merge SEG partial top-13s -> global top-13 per (b,n)
__global__ __launch_bounds__(256) void topk_merge_kernel(
    const float* __restrict__ pv, const int* __restrict__ pi,
    float* __restrict__ tv, int* __restrict__ ti)
{
  const int bn = blockIdx.x;
  const int t = threadIdx.x;
  const int NC = SEG*TOPKK;        // 208
  float v = -2.f; int ix = 0x7fffffff;
  if (t < NC){ v = pv[bn*NC + t]; ix = pi[bn*NC + t]; }
  __shared__ float sv[256]; __shared__ int si[256]; __shared__ int sl[256];
  for (int k=0;k<13;++k){
    sv[t]=v; si[t]=ix; sl[t]=t;
    __syncthreads();
    for (int s2=128;s2;s2>>=1){
      if (t<s2){
        if (sv[t+s2]>sv[t] || (sv[t+s2]==sv[t] && si[t+s2]<si[t])){
          sv[t]=sv[t+s2]; si[t]=si[t+s2]; sl[t]=sl[t+s2];
        }
      }
      __syncthreads();
    }
    if (t==0){ tv[bn*TOPKK+k]=sv[0]; ti[bn*TOPKK+k]=si[0]; }
    int win = sl[0];
    __syncthreads();
    if (t==win) v = -2.f;
  }
}

// ---------------- Phase C: parallel candidate resolution via LDS hash table
__global__ __launch_bounds__(512) void finalize_kernel(
    const float* __restrict__ logits_ws, const float* __restrict__ centers_ws,
    const float* __restrict__ labels,
    const float* __restrict__ tv, const int* __restrict__ ti,
    const float* __restrict__ bg_sum, float* __restrict__ out)
{
  const int tid = threadIdx.x;   // 512
  __shared__ float gx[32], gy[32], gz[32], gs[32];
  __shared__ int glab[32], gvalid[32];
  __shared__ int hkey[1024], hcnt[1024], hmin[1024];
  __shared__ unsigned maxA[32], maxI[32];
  __shared__ float accD, accC;
  if (tid==0){ accD=0.f; accC=0.f; }

  for (int b=0;b<NB;++b){
    for (int i=tid;i<1024;i+=512){ hkey[i]=-1; hcnt[i]=0; hmin[i]=0x7fffffff; }
    if (tid<32){
      const float* lb = labels + (b*NMAXG + tid)*5;
      gx[tid]=lb[0]; gy[tid]=lb[1]; gz[tid]=lb[2];
      float cf = lb[3]; gs[tid]=lb[4];
      int val = (cf != -100.f);
      gvalid[tid]=val; glab[tid]= val ? (int)cf : 0;
      maxA[tid]=0u; maxI[tid]=0u;
    }
    __syncthreads();

    const int e = tid;
    bool ok = false; int l = -1; int n = 0;
    if (e < 416){
      n = e/13; int k = e - 13*n;
      float v = tv[(b*NMAXG+n)*TOPKK + k];
      l = ti[(b*NMAXG+n)*TOPKK + k];
      ok = gvalid[n] && (v > 1e-9f);
    }
    int slot = -1;
    if (ok){
      unsigned h = (((unsigned)l * 2654435761u) >> 20) & 1023u;
      for (;;){
        int prev = atomicCAS(&hkey[h], -1, l);
        if (prev == -1 || prev == l){ slot = (int)h; break; }
        h = (h+1) & 1023u;
      }
      atomicAdd(&hcnt[slot], 1);
      atomicMin(&hmin[slot], e);
    }
    __syncthreads();

    bool first = ok && (hmin[slot] == e);
    float a=0.f, iou=0.f; int nstar=0;
    if (first){
      float px = centers_ws[((size_t)b*LL + l)*4 + 0];
      float py = centers_ws[((size_t)b*LL + l)*4 + 1];
      float pz = centers_ws[((size_t)b*LL + l)*4 + 2];
      if (hcnt[slot] == 1){
        nstar = n;
      } else {
        float best = -1.f; int bidx = 0;
        for (int nn=0;nn<32;++nn){
          float dx=gx[nn]-px, dy=gy[nn]-py, dz=gz[nn]-pz;
          float d2 = dx*dx+dy*dy+dz*dz;
          float io = expf(-d2/(2.f*gs[nn]*gs[nn]));
          if (io > best){ best=io; bidx=nn; }
        }
        nstar = bidx;
      }
      float dx=gx[nstar]-px, dy=gy[nstar]-py, dz=gz[nstar]-pz;
      float d2 = dx*dx+dy*dy+dz*dz;
      float sgv = gs[nstar];
      iou = expf(-d2/(2.f*sgv*sgv));
      float z = logits_ws[(size_t)(b*NCLS + glab[nstar])*LL + l];
      a = sigmoidf_(z) * expf(-3.f*d2/(sgv*sgv));
      atomicMax(&maxA[nstar], __float_as_uint(a));
      atomicMax(&maxI[nstar], __float_as_uint(iou));
    }
    __syncthreads();

    if (first){
      float mA = __uint_as_float(maxA[nstar]);
      float mI = __uint_as_float(maxI[nstar]);
      float score = a*mI/(mA + 1e-9f);
      float z = logits_ws[(size_t)(b*NCLS + glab[nstar])*LL + l];
      float p = sigmoidf_(z);
      float t2 = log1pf(expf(-fabsf(z)));
      float spz = fmaxf(z,0.f) + t2;
      float spm = fmaxf(-z,0.f) + t2;
      float corr = score*(score*spm + (1.f-score)*spz) - 0.75f*p*p*spz;
      float reg  = (1.f - iou)*score;
      atomicAdd(&accD, score);
      atomicAdd(&accC, corr + reg);
    }
    __syncthreads();
  }
  if (tid==0) out[0] = (bg_sum[0] + accC) / accD;
}

extern "C" void kernel_launch(void* const* d_in, const int* in_sizes, int n_in,
                              void* d_out, int out_size, void* d_ws, size_t ws_size,
                              hipStream_t stream) {
  const float* feat  = (const float*)d_in[0];
  const float* cls_w = (const float*)d_in[1];
  const float* cls_b = (const float*)d_in[2];
  const float* off_w = (const float*)d_in[3];
  const float* off_b = (const float*)d_in[4];
  const float* labels= (const float*)d_in[5];
  float* out = (float*)d_out;

  float* logits_ws  = (float*)d_ws;                              // 2*5*L
  float* centers_ws = logits_ws + (size_t)NB*NCLS*LL;            // 2*L*4
  float* pv = centers_ws + (size_t)NB*LL*4;                      // 64*SEG*13
  int*   pi = (int*)(pv + 64*SEG*TOPKK);
  float* tv = (float*)(pi + 64*SEG*TOPKK);                       // 64*13
  int*   ti = (int*)(tv + 64*TOPKK);
  float* bg = (float*)(ti + 64*TOPKK);                           // +16 pad
  short* wA = (short*)(bg + 16);                                 // 72*64*8 bf16

  hipMemsetAsync(bg, 0, sizeof(float), stream);

  wtrans_kernel<<<18, 256, 0, stream>>>(cls_w, off_w, wA);
  conv_mfma_kernel<<<dim3(16,16,2), 512, 0, stream>>>(
      feat, wA, cls_b, off_b, logits_ws, centers_ws, bg);
  topk_partial_kernel<<<dim3(64,SEG), 256, 0, stream>>>(
      logits_ws, centers_ws, labels, pv, pi);
  topk_merge_kernel<<<64, 256, 0, stream>>>(pv, pi, tv, ti);
  finalize_kernel<<<1, 512, 0, stream>>>(
      logits_ws, centers_ws, labels, tv, ti, bg, out);
}